// Round 1
// baseline (82.107 us; speedup 1.0000x reference)
//
#include <hip/hip_runtime.h>
#include <hip/hip_bf16.h>
#include <math.h>

#define NN 768
#define DD 64
#define SS 32
#define PP 4

// mu = linspace(0,12,32) -> step 12/31 ; sigma = 12/32 -> 1/(2 sigma^2)
#define MU_STEP   (12.0f / 31.0f)
#define INV2SIG2  3.55555555555f

// ---------------------------------------------------------------------------
// Kernel 1: T[x][j*32+s] = sum_i hid[x][i] * W[i][j][s]
// Flattened: T = H (768x64) @ W' (64x2048), c = j*32+s, W'[i][c]=W[i*2048+c]
// grid = 192 blocks (4 c-blocks x 48 x-blocks), 256 threads
// ---------------------------------------------------------------------------
__global__ __launch_bounds__(256) void k1_T(const float* __restrict__ hid,
                                            const float* __restrict__ W,
                                            float* __restrict__ T) {
    const int b   = blockIdx.x;
    const int cb  = b & 3;        // c0 = cb*512
    const int xb  = b >> 2;       // x0 = xb*16
    const int c0  = cb * 512;
    const int x0  = xb * 16;
    const int tid = threadIdx.x;
    const int ct  = tid & 63;     // 0..63 -> 8 c's each
    const int xt  = tid >> 6;     // 0..3  -> 4 x's each

    __shared__ float hs[16 * 64];
    {
        const float4 v = *reinterpret_cast<const float4*>(&hid[(size_t)x0 * 64 + tid * 4]);
        float4* dst = reinterpret_cast<float4*>(&hs[tid * 4]);
        *dst = v;
    }
    __syncthreads();

    float acc[4][8];
#pragma unroll
    for (int m = 0; m < 4; ++m)
#pragma unroll
        for (int u = 0; u < 8; ++u) acc[m][u] = 0.0f;

    const int cbase = c0 + ct * 8;
#pragma unroll 4
    for (int i = 0; i < 64; ++i) {
        const float4 w0 = *reinterpret_cast<const float4*>(&W[(size_t)i * 2048 + cbase]);
        const float4 w1 = *reinterpret_cast<const float4*>(&W[(size_t)i * 2048 + cbase + 4]);
#pragma unroll
        for (int m = 0; m < 4; ++m) {
            const float hm = hs[(xt * 4 + m) * 64 + i];
            acc[m][0] += hm * w0.x;
            acc[m][1] += hm * w0.y;
            acc[m][2] += hm * w0.z;
            acc[m][3] += hm * w0.w;
            acc[m][4] += hm * w1.x;
            acc[m][5] += hm * w1.y;
            acc[m][6] += hm * w1.z;
            acc[m][7] += hm * w1.w;
        }
    }

#pragma unroll
    for (int m = 0; m < 4; ++m) {
        const int x = x0 + xt * 4 + m;
        float4 o0, o1;
        o0.x = acc[m][0]; o0.y = acc[m][1]; o0.z = acc[m][2]; o0.w = acc[m][3];
        o1.x = acc[m][4]; o1.y = acc[m][5]; o1.z = acc[m][6]; o1.w = acc[m][7];
        *reinterpret_cast<float4*>(&T[(size_t)x * 2048 + cbase])     = o0;
        *reinterpret_cast<float4*>(&T[(size_t)x * 2048 + cbase + 4]) = o1;
    }
}

// ---------------------------------------------------------------------------
// Kernel 2: fused   inter-GEMM  +  rbf epilogue  +  block reduction
// One block per x (768 blocks), 256 threads = 4 waves.
//   wave ts (=tid>>6) owns s-block [ts*8, ts*8+8)
//   lane ty (=tid&63) owns 3 y rows per 192-row chunk (4 chunks)
// T_l  : T[x] in LDS, reads are wave-uniform (broadcast)
// h_t  : transposed hid chunk [j][y], b32 reads at bank stride 3 (2-way, free)
// ---------------------------------------------------------------------------
template <bool USE_WS_T>
__global__ __launch_bounds__(256) void k2_main(const float* __restrict__ hid,
                                               const float* __restrict__ coords,
                                               const float* __restrict__ W,
                                               const float* __restrict__ b_rbf,
                                               const float* __restrict__ Tg,
                                               float* __restrict__ partials) {
    const int x   = blockIdx.x;
    const int tid = threadIdx.x;
    const int ty  = tid & 63;
    const int ts  = tid >> 6;

    __shared__ float T_l[2048];          // 8 KB
    __shared__ float h_t[64 * 192];      // 48 KB, [j][y] transposed
    __shared__ float4 red[256];          // 4 KB
    __shared__ float hx[64];

    if (USE_WS_T) {
        const float4 a = *reinterpret_cast<const float4*>(&Tg[(size_t)x * 2048 + tid * 8]);
        const float4 b = *reinterpret_cast<const float4*>(&Tg[(size_t)x * 2048 + tid * 8 + 4]);
        *reinterpret_cast<float4*>(&T_l[tid * 8])     = a;
        *reinterpret_cast<float4*>(&T_l[tid * 8 + 4]) = b;
    } else {
        if (tid < 64) hx[tid] = hid[(size_t)x * 64 + tid];
        __syncthreads();
        float a0[4] = {0, 0, 0, 0}, a1[4] = {0, 0, 0, 0};
        for (int i = 0; i < 64; ++i) {
            const float hv = hx[i];
            const float4 w0 = *reinterpret_cast<const float4*>(&W[(size_t)i * 2048 + tid * 4]);
            const float4 w1 = *reinterpret_cast<const float4*>(&W[(size_t)i * 2048 + 1024 + tid * 4]);
            a0[0] += hv * w0.x; a0[1] += hv * w0.y; a0[2] += hv * w0.z; a0[3] += hv * w0.w;
            a1[0] += hv * w1.x; a1[1] += hv * w1.y; a1[2] += hv * w1.z; a1[3] += hv * w1.w;
        }
        T_l[tid * 4 + 0] = a0[0]; T_l[tid * 4 + 1] = a0[1];
        T_l[tid * 4 + 2] = a0[2]; T_l[tid * 4 + 3] = a0[3];
        T_l[1024 + tid * 4 + 0] = a1[0]; T_l[1024 + tid * 4 + 1] = a1[1];
        T_l[1024 + tid * 4 + 2] = a1[2]; T_l[1024 + tid * 4 + 3] = a1[3];
    }

    // per-wave rbf constants
    float mu_reg[8], b_reg[8];
#pragma unroll
    for (int u = 0; u < 8; ++u) {
        const int s = ts * 8 + u;
        mu_reg[u] = (float)s * MU_STEP;
        b_reg[u]  = b_rbf[s];
    }
    // this x's coordinates (uniform across block)
    float cx[PP][3];
#pragma unroll
    for (int p = 0; p < PP; ++p)
#pragma unroll
        for (int c = 0; c < 3; ++c)
            cx[p][c] = coords[(size_t)p * NN * 3 + (size_t)x * 3 + c];

    float e[PP] = {0.0f, 0.0f, 0.0f, 0.0f};

    for (int ch = 0; ch < 4; ++ch) {
        const int yc = ch * 192;
        __syncthreads();  // protect h_t (and T_l on first iter)
        if (tid < 192) {
            const int y = yc + tid;
#pragma unroll
            for (int r = 0; r < 16; ++r) {
                const float4 v = *reinterpret_cast<const float4*>(&hid[(size_t)y * 64 + r * 4]);
                h_t[(r * 4 + 0) * 192 + tid] = v.x;
                h_t[(r * 4 + 1) * 192 + tid] = v.y;
                h_t[(r * 4 + 2) * 192 + tid] = v.z;
                h_t[(r * 4 + 3) * 192 + tid] = v.w;
            }
        }
        __syncthreads();

        float acc[3][8];
#pragma unroll
        for (int i = 0; i < 3; ++i)
#pragma unroll
            for (int u = 0; u < 8; ++u) acc[i][u] = 0.0f;

#pragma unroll 4
        for (int j = 0; j < 64; ++j) {
            const float h0 = h_t[j * 192 + ty * 3 + 0];
            const float h1 = h_t[j * 192 + ty * 3 + 1];
            const float h2 = h_t[j * 192 + ty * 3 + 2];
            const float4 t0 = *reinterpret_cast<const float4*>(&T_l[j * 32 + ts * 8]);
            const float4 t1 = *reinterpret_cast<const float4*>(&T_l[j * 32 + ts * 8 + 4]);
            acc[0][0] += h0 * t0.x; acc[0][1] += h0 * t0.y; acc[0][2] += h0 * t0.z; acc[0][3] += h0 * t0.w;
            acc[0][4] += h0 * t1.x; acc[0][5] += h0 * t1.y; acc[0][6] += h0 * t1.z; acc[0][7] += h0 * t1.w;
            acc[1][0] += h1 * t0.x; acc[1][1] += h1 * t0.y; acc[1][2] += h1 * t0.z; acc[1][3] += h1 * t0.w;
            acc[1][4] += h1 * t1.x; acc[1][5] += h1 * t1.y; acc[1][6] += h1 * t1.z; acc[1][7] += h1 * t1.w;
            acc[2][0] += h2 * t0.x; acc[2][1] += h2 * t0.y; acc[2][2] += h2 * t0.z; acc[2][3] += h2 * t0.w;
            acc[2][4] += h2 * t1.x; acc[2][5] += h2 * t1.y; acc[2][6] += h2 * t1.z; acc[2][7] += h2 * t1.w;
        }

        // rbf epilogue for this thread's 3 y rows
#pragma unroll
        for (int i = 0; i < 3; ++i) {
            const int y = yc + ty * 3 + i;
            if (y == x) continue;  // diagonal mask
#pragma unroll
            for (int p = 0; p < PP; ++p) {
                const float dx = cx[p][0] - coords[(size_t)p * NN * 3 + (size_t)y * 3 + 0];
                const float dy = cx[p][1] - coords[(size_t)p * NN * 3 + (size_t)y * 3 + 1];
                const float dz = cx[p][2] - coords[(size_t)p * NN * 3 + (size_t)y * 3 + 2];
                const float d  = sqrtf(dx * dx + dy * dy + dz * dz + 1e-12f);
                float ep = 0.0f;
#pragma unroll
                for (int u = 0; u < 8; ++u) {
                    const float t = d - mu_reg[u];
                    const float w = __expf(-(t * t) * INV2SIG2);
                    ep += (acc[i][u] + b_reg[u]) * w;
                }
                e[p] += ep;
            }
        }
    }

    // deterministic block reduction (fixed tree)
    __syncthreads();
    float4 ev; ev.x = e[0]; ev.y = e[1]; ev.z = e[2]; ev.w = e[3];
    red[tid] = ev;
    __syncthreads();
#pragma unroll
    for (int st = 128; st >= 1; st >>= 1) {
        if (tid < st) {
            float4 a = red[tid], b = red[tid + st];
            a.x += b.x; a.y += b.y; a.z += b.z; a.w += b.w;
            red[tid] = a;
        }
        __syncthreads();
    }
    if (tid == 0) *reinterpret_cast<float4*>(&partials[(size_t)x * 4]) = red[0];
}

// ---------------------------------------------------------------------------
// Kernel 3: deterministic final reduction of 768 block partials -> U[4]
// 4 waves; wave p sums its 768 values in fixed order, butterfly reduce.
// ---------------------------------------------------------------------------
__global__ __launch_bounds__(256) void k3_final(const float* __restrict__ partials,
                                                const float* __restrict__ weight,
                                                const float* __restrict__ bias_,
                                                float* __restrict__ out) {
    const int p    = threadIdx.x >> 6;
    const int lane = threadIdx.x & 63;
    float s = 0.0f;
#pragma unroll
    for (int k = 0; k < 12; ++k) s += partials[(size_t)(lane * 12 + k) * 4 + p];
#pragma unroll
    for (int off = 1; off < 64; off <<= 1) s += __shfl_xor(s, off, 64);
    if (lane == 0)
        out[p] = s * (1.0f / 18874368.0f) * weight[0] + bias_[0];  // /(N*N*S)
}

// ---------------------------------------------------------------------------
extern "C" void kernel_launch(void* const* d_in, const int* in_sizes, int n_in,
                              void* d_out, int out_size, void* d_ws, size_t ws_size,
                              hipStream_t stream) {
    const float* hid    = (const float*)d_in[0];
    const float* coords = (const float*)d_in[1];
    const float* W      = (const float*)d_in[2];
    const float* b_rbf  = (const float*)d_in[3];
    const float* weight = (const float*)d_in[4];
    const float* bias_  = (const float*)d_in[5];
    float* out = (float*)d_out;

    const size_t T_BYTES    = (size_t)NN * 2048 * sizeof(float);   // 6.29 MB
    const size_t PART_BYTES = (size_t)NN * 4 * sizeof(float);      // 12 KB
    const bool use_ws = ws_size >= T_BYTES + PART_BYTES;

    float* Tg       = (float*)d_ws;
    float* partials = use_ws ? (float*)((char*)d_ws + T_BYTES) : (float*)d_ws;

    if (use_ws) {
        k1_T<<<192, 256, 0, stream>>>(hid, W, Tg);
        k2_main<true><<<NN, 256, 0, stream>>>(hid, coords, W, b_rbf, Tg, partials);
    } else {
        // fallback: each block recomputes T[x] from W (extra L2 traffic only)
        k2_main<false><<<NN, 256, 0, stream>>>(hid, coords, W, b_rbf, nullptr, partials);
    }
    k3_final<<<1, 256, 0, stream>>>(partials, weight, bias_, out);
}